// Round 1
// baseline (70.594 us; speedup 1.0000x reference)
//
#include <hip/hip_runtime.h>
#include <math.h>

#define BB 4
#define SS 4096
#define DD 256
#define HALFD 128

// ---------------------------------------------------------------------------
// K1: q[b][h] = sum_i x[b,0,i] * W0[i,h]   (RoPE at pos 0 is identity)
// grid (4, 8): block = (batch, 32-col chunk); 256 thr = 8 i-segments x 32 cols
// ---------------------------------------------------------------------------
__global__ __launch_bounds__(256) void qkernel(const float* __restrict__ x,
                                               const float* __restrict__ W0,
                                               float* __restrict__ q) {
    const int b = blockIdx.x;
    const int hc = blockIdx.y;
    const int tid = threadIdx.x;
    const int hk = tid & 31;
    const int iseg = tid >> 5;
    const int h = hc * 32 + hk;
    const float* xrow = x + (size_t)b * SS * DD;  // position 0 row
    float p = 0.f;
#pragma unroll
    for (int k = 0; k < 32; ++k) {
        const int i = iseg * 32 + k;
        p = fmaf(xrow[i], W0[i * DD + h], p);
    }
    __shared__ float red[256];
    red[tid] = p;
    __syncthreads();
    if (tid < 32) {
        float s = 0.f;
#pragma unroll
        for (int j = 0; j < 8; ++j) s += red[j * 32 + tid];
        q[b * DD + hc * 32 + tid] = s;
    }
}

// ---------------------------------------------------------------------------
// K2: scores[b][t] = q_b . R_t( x[b,t,:] @ W1 )
// grid 512 (4 batches x 128 row-blocks of 32), block 128 thr (2 waves).
// Thread tile: 8 rows x 8 cols of the v = x@W1 intermediate (64 fp32 acc).
// Wave: lanes 0-31 -> cols 0..255 (8 each) for rows rl..rl+7,
//       lanes 32-63 -> same cols for rows rl+8..rl+15.
// x rows staged transposed in LDS (xsT[i][r]); W1 streamed from global (L1/L2).
// Epilogue: RoPE rotation folded into dot with q, half-wave shuffle reduce.
// ---------------------------------------------------------------------------
__global__ __launch_bounds__(128) void scores_kernel(const float* __restrict__ x,
                                                     const float* __restrict__ W1,
                                                     const float* __restrict__ q,
                                                     float* __restrict__ scores) {
    __shared__ float xsT[256][32];  // 32 KB, i-major, row-minor
    const int tid = threadIdx.x;
    const int bid = blockIdx.x;
    const int b = bid >> 7;
    const int row0 = (bid & 127) << 5;

    // ---- stage x[b, row0 .. row0+31, :] transposed into LDS ----
    {
        const int r = tid >> 2;                  // 32 rows, 4 threads each
        const int q4 = tid & 3;                  // 64-col quarter
        const float* xr = x + ((size_t)(b * SS + row0 + r)) * DD + q4 * 64;
#pragma unroll
        for (int k = 0; k < 16; ++k) {
            const float4 v = *(const float4*)(xr + k * 4);
            const int i = q4 * 64 + k * 4;
            xsT[i + 0][r] = v.x;
            xsT[i + 1][r] = v.y;
            xsT[i + 2][r] = v.z;
            xsT[i + 3][r] = v.w;
        }
    }
    __syncthreads();

    const int lane = tid & 63;
    const int wv = tid >> 6;        // wave id (0..1)
    const int cg = lane & 31;       // col group
    const int hf = lane >> 5;       // half-wave
    const int h0 = cg << 3;         // first of 8 columns
    const int rl = wv * 16 + hf * 8;  // first of 8 local rows

    float acc[8][8];
#pragma unroll
    for (int a = 0; a < 8; ++a)
#pragma unroll
        for (int c = 0; c < 8; ++c) acc[a][c] = 0.f;

    const float* Wp = W1 + h0;
#pragma unroll 4
    for (int i = 0; i < 256; ++i) {
        const float4 xa = *(const float4*)&xsT[i][rl];
        const float4 xb = *(const float4*)&xsT[i][rl + 4];
        const float4 wa = *(const float4*)(Wp + i * DD);
        const float4 wb = *(const float4*)(Wp + i * DD + 4);
        const float xr[8] = {xa.x, xa.y, xa.z, xa.w, xb.x, xb.y, xb.z, xb.w};
        const float wc[8] = {wa.x, wa.y, wa.z, wa.w, wb.x, wb.y, wb.z, wb.w};
#pragma unroll
        for (int a = 0; a < 8; ++a)
#pragma unroll
            for (int c = 0; c < 8; ++c) acc[a][c] = fmaf(xr[a], wc[c], acc[a][c]);
    }

    // ---- epilogue: RoPE + dot with q + half-wave reduction ----
    const float4 q0 = *(const float4*)(q + b * DD + h0);
    const float4 q1 = *(const float4*)(q + b * DD + h0 + 4);
    const float qv[8] = {q0.x, q0.y, q0.z, q0.w, q1.x, q1.y, q1.z, q1.w};

    const float kfac = (float)(-9.210340371976184 / 128.0);  // -ln(10000)/128
    float div4[4];
#pragma unroll
    for (int j = 0; j < 4; ++j) div4[j] = expf((float)(cg * 4 + j) * kfac);

#pragma unroll
    for (int rr = 0; rr < 8; ++rr) {
        const int t = row0 + rl + rr;
        const float tf = (float)t;
        float partial = 0.f;
#pragma unroll
        for (int j = 0; j < 4; ++j) {
            float sv, cv;
            sincosf(tf * div4[j], &sv, &cv);
            const float ve = acc[rr][2 * j], vo = acc[rr][2 * j + 1];
            // q_e*(ve*c - vo*s) + q_o*(ve*s + vo*c)
            partial += qv[2 * j] * (ve * cv - vo * sv) + qv[2 * j + 1] * (ve * sv + vo * cv);
        }
#pragma unroll
        for (int off = 16; off >= 1; off >>= 1) partial += __shfl_xor(partial, off);
        if (cg == 0) scores[(size_t)b * SS + t] = partial;
    }
}

// ---------------------------------------------------------------------------
// K3: in-place softmax over scores[b][0..4095]. grid 4, block 1024.
// ---------------------------------------------------------------------------
__global__ __launch_bounds__(1024) void softmax_kernel(float* __restrict__ sc) {
    const int b = blockIdx.x;
    const int tid = threadIdx.x;
    const int lane = tid & 63;
    const int wid = tid >> 6;
    float4* p = (float4*)(sc + (size_t)b * SS);
    float4 v = p[tid];

    float m = fmaxf(fmaxf(v.x, v.y), fmaxf(v.z, v.w));
#pragma unroll
    for (int off = 32; off >= 1; off >>= 1) m = fmaxf(m, __shfl_xor(m, off));
    __shared__ float redm[16];
    __shared__ float reds[16];
    if (lane == 0) redm[wid] = m;
    __syncthreads();
    if (tid == 0) {
        float M = redm[0];
#pragma unroll
        for (int j = 1; j < 16; ++j) M = fmaxf(M, redm[j]);
        redm[0] = M;
    }
    __syncthreads();
    const float M = redm[0];

    float4 e;
    e.x = expf(v.x - M);
    e.y = expf(v.y - M);
    e.z = expf(v.z - M);
    e.w = expf(v.w - M);
    float s = e.x + e.y + e.z + e.w;
#pragma unroll
    for (int off = 32; off >= 1; off >>= 1) s += __shfl_xor(s, off);
    if (lane == 0) reds[wid] = s;
    __syncthreads();
    if (tid == 0) {
        float T = 0.f;
#pragma unroll
        for (int j = 0; j < 16; ++j) T += reds[j];
        reds[0] = T;
    }
    __syncthreads();
    const float inv = 1.0f / reds[0];
    e.x *= inv;
    e.y *= inv;
    e.z *= inv;
    e.w *= inv;
    p[tid] = e;
}

// ---------------------------------------------------------------------------
// K4: y[b][o] = sum_t attn[b][t] * x[b,t,o]   (attn is ~one-hot: skip zeros)
// grid (64 chunks, 4 b), block 256. Partial sums via fp32 global atomics.
// ---------------------------------------------------------------------------
__global__ __launch_bounds__(256) void wsum_kernel(const float* __restrict__ x,
                                                   const float* __restrict__ attn,
                                                   float* __restrict__ y) {
    const int c = blockIdx.x;
    const int b = blockIdx.y;
    const int tid = threadIdx.x;
    const int t0 = c * 64;
    __shared__ float a_s[64];
    if (tid < 64) a_s[tid] = attn[(size_t)b * SS + t0 + tid];
    __syncthreads();
    float acc = 0.f;
    for (int t = 0; t < 64; ++t) {
        const float a = a_s[t];
        if (a != 0.f)  // uniform branch; exp-underflowed rows cost nothing
            acc = fmaf(a, x[((size_t)(b * SS + t0 + t)) * DD + tid], acc);
    }
    atomicAdd(&y[b * DD + tid], acc);
}

// ---------------------------------------------------------------------------
// K5: out[b][o] = sum_i y[b][i] * W2[i][o].  grid 32 (4 b x 8 i-chunks).
// ---------------------------------------------------------------------------
__global__ __launch_bounds__(256) void out_kernel(const float* __restrict__ y,
                                                  const float* __restrict__ W2,
                                                  float* __restrict__ out) {
    const int bx = blockIdx.x;
    const int b = bx >> 3;
    const int i0 = (bx & 7) * 32;
    const int tid = threadIdx.x;
    __shared__ float y_s[32];
    if (tid < 32) y_s[tid] = y[b * DD + i0 + tid];
    __syncthreads();
    float p = 0.f;
#pragma unroll
    for (int ii = 0; ii < 32; ++ii) p = fmaf(y_s[ii], W2[(size_t)(i0 + ii) * DD + tid], p);
    atomicAdd(&out[b * DD + tid], p);
}

// ---------------------------------------------------------------------------
extern "C" void kernel_launch(void* const* d_in, const int* in_sizes, int n_in,
                              void* d_out, int out_size, void* d_ws, size_t ws_size,
                              hipStream_t stream) {
    const float* x = (const float*)d_in[0];
    const float* W0 = (const float*)d_in[1];
    const float* W1 = (const float*)d_in[2];
    const float* W2 = (const float*)d_in[3];
    float* ws = (float*)d_ws;
    float* q = ws;                    // 1024 floats
    float* scores = ws + 1024;        // 16384 floats
    float* y = ws + 1024 + 16384;     // 1024 floats
    float* out = (float*)d_out;       // 1024 floats (fp32)

    hipMemsetAsync(y, 0, BB * DD * sizeof(float), stream);
    hipMemsetAsync(d_out, 0, BB * DD * sizeof(float), stream);

    qkernel<<<dim3(BB, 8), 256, 0, stream>>>(x, W0, q);
    scores_kernel<<<dim3(512), 128, 0, stream>>>(x, W1, q, scores);
    softmax_kernel<<<dim3(BB), 1024, 0, stream>>>(scores);
    wsum_kernel<<<dim3(64, BB), 256, 0, stream>>>(x, scores, y);
    out_kernel<<<dim3(32), 256, 0, stream>>>(y, W2, out);
}

// Round 2
// 62.444 us; speedup vs baseline: 1.1305x; 1.1305x over previous
//
#include <hip/hip_runtime.h>
#include <math.h>

#define BB 4
#define SS 4096
#define DD 256
#define HALFD 128

// ---------------------------------------------------------------------------
// K1: q[b][h] = sum_i x[b,0,i] * W0[i,h]   (RoPE at pos 0 is identity)
// ---------------------------------------------------------------------------
__global__ __launch_bounds__(256) void qkernel(const float* __restrict__ x,
                                               const float* __restrict__ W0,
                                               float* __restrict__ q) {
    const int b = blockIdx.x;
    const int hc = blockIdx.y;
    const int tid = threadIdx.x;
    const int hk = tid & 31;
    const int iseg = tid >> 5;
    const int h = hc * 32 + hk;
    const float* xrow = x + (size_t)b * SS * DD;  // position 0 row
    float p = 0.f;
#pragma unroll
    for (int k = 0; k < 32; ++k) {
        const int i = iseg * 32 + k;
        p = fmaf(xrow[i], W0[i * DD + h], p);
    }
    __shared__ float red[256];
    red[tid] = p;
    __syncthreads();
    if (tid < 32) {
        float s = 0.f;
#pragma unroll
        for (int j = 0; j < 8; ++j) s += red[j * 32 + tid];
        q[b * DD + hc * 32 + tid] = s;
    }
}

// ---------------------------------------------------------------------------
// K2: scores[b][t] = q_b . R_t( x[b,t,:] @ W1 )
// grid 1024 (4 b x 256 row-blocks of 16), block 256 thr (4 waves).
// In-block k-split: waves 0-1 -> k[0,128), waves 2-3 -> k[128,256).
// Within a k-half, wave wr=wv&1 owns rows wr*8..wr*8+7; lane: cg=lane&31 ->
// cols cg*8..cg*8+7, hf=lane>>5 -> rows +hf*4. Per-thread 4x8 fp32 acc.
// x staged transposed+swizzled in LDS; W1 streamed (L2-resident).
// kh==1 waves dump partials to LDS; kh==0 waves combine + RoPE-dot epilogue.
// Trig expressions kept bit-identical to the validated version.
// ---------------------------------------------------------------------------
__global__ __launch_bounds__(256) void scores_kernel(const float* __restrict__ x,
                                                     const float* __restrict__ W1,
                                                     const float* __restrict__ q,
                                                     float* __restrict__ scores) {
    __shared__ float xsT[256][16];  // 16 KB; reused as 32x128 combine buffer
    const int tid = threadIdx.x;
    const int bid = blockIdx.x;
    const int b = bid >> 8;
    const int row0 = (bid & 255) << 4;

    // ---- stage x[b, row0..row0+15, :] transposed into LDS (swizzled) ----
    {
        const int r = tid >> 4;       // 16 rows, 16 threads each
        const int cs = tid & 15;      // 16-float k-segment
        const int sx = (cs & 3) << 2; // XOR swizzle: 16-way -> 4-way on writes
        const float* xr = x + ((size_t)(b * SS + row0 + r)) * DD + cs * 16;
#pragma unroll
        for (int k4 = 0; k4 < 4; ++k4) {
            const float4 v = *(const float4*)(xr + k4 * 4);
            const int k = cs * 16 + k4 * 4;
            xsT[k + 0][r ^ sx] = v.x;
            xsT[k + 1][r ^ sx] = v.y;
            xsT[k + 2][r ^ sx] = v.z;
            xsT[k + 3][r ^ sx] = v.w;
        }
    }
    __syncthreads();

    const int lane = tid & 63;
    const int wv = tid >> 6;     // wave id 0..3
    const int kh = wv >> 1;      // k-half
    const int wr = wv & 1;       // row-half of the block
    const int cg = lane & 31;    // col group (8 cols)
    const int hf = lane >> 5;    // row sub-group (4 rows)
    const int h0 = cg << 3;
    const int rbase = wr * 8 + hf * 4;  // local row of first acc row

    float acc[4][8];
#pragma unroll
    for (int a = 0; a < 4; ++a)
#pragma unroll
        for (int c = 0; c < 8; ++c) acc[a][c] = 0.f;

    const float* Wp = W1 + h0;
    const int k0 = kh * 128;
#pragma unroll 4
    for (int k = k0; k < k0 + 128; ++k) {
        const int sw = rbase ^ (((k >> 4) & 3) << 2);
        const float4 xa = *(const float4*)&xsT[k][sw];
        const float4 wa = *(const float4*)(Wp + k * DD);
        const float4 wb = *(const float4*)(Wp + k * DD + 4);
        const float xr4[4] = {xa.x, xa.y, xa.z, xa.w};
        const float wc[8] = {wa.x, wa.y, wa.z, wa.w, wb.x, wb.y, wb.z, wb.w};
#pragma unroll
        for (int a = 0; a < 4; ++a)
#pragma unroll
            for (int c = 0; c < 8; ++c) acc[a][c] = fmaf(xr4[a], wc[c], acc[a][c]);
    }

    // ---- combine k-halves through LDS (reuse xsT memory) ----
    __syncthreads();  // everyone done reading xsT
    float* comb = &xsT[0][0];  // [32 acc-idx][128 = wr*64+lane]
    if (kh == 1) {
#pragma unroll
        for (int a = 0; a < 4; ++a)
#pragma unroll
            for (int c = 0; c < 8; ++c)
                comb[(a * 8 + c) * 128 + wr * 64 + lane] = acc[a][c];
    }
    __syncthreads();
    if (kh == 0) {
#pragma unroll
        for (int a = 0; a < 4; ++a)
#pragma unroll
            for (int c = 0; c < 8; ++c)
                acc[a][c] += comb[(a * 8 + c) * 128 + wr * 64 + lane];

        // ---- epilogue: RoPE + dot with q + 32-lane shuffle reduction ----
        const float4 q0 = *(const float4*)(q + b * DD + h0);
        const float4 q1 = *(const float4*)(q + b * DD + h0 + 4);
        const float qv[8] = {q0.x, q0.y, q0.z, q0.w, q1.x, q1.y, q1.z, q1.w};

        const float kfac = (float)(-9.210340371976184 / 128.0);  // -ln(1e4)/128
        float div4[4];
#pragma unroll
        for (int j = 0; j < 4; ++j) div4[j] = expf((float)(cg * 4 + j) * kfac);

#pragma unroll
        for (int rr = 0; rr < 4; ++rr) {
            const int t = row0 + rbase + rr;
            const float tf = (float)t;
            float partial = 0.f;
#pragma unroll
            for (int j = 0; j < 4; ++j) {
                float sv, cv;
                sincosf(tf * div4[j], &sv, &cv);
                const float ve = acc[rr][2 * j], vo = acc[rr][2 * j + 1];
                partial += qv[2 * j] * (ve * cv - vo * sv) + qv[2 * j + 1] * (ve * sv + vo * cv);
            }
#pragma unroll
            for (int off = 16; off >= 1; off >>= 1) partial += __shfl_xor(partial, off);
            if (cg == 0) scores[(size_t)b * SS + t] = partial;
        }
    }
}

// ---------------------------------------------------------------------------
// K3: in-place softmax over scores[b][0..4095]. grid 4, block 1024.
// ---------------------------------------------------------------------------
__global__ __launch_bounds__(1024) void softmax_kernel(float* __restrict__ sc) {
    const int b = blockIdx.x;
    const int tid = threadIdx.x;
    const int lane = tid & 63;
    const int wid = tid >> 6;
    float4* p = (float4*)(sc + (size_t)b * SS);
    float4 v = p[tid];

    float m = fmaxf(fmaxf(v.x, v.y), fmaxf(v.z, v.w));
#pragma unroll
    for (int off = 32; off >= 1; off >>= 1) m = fmaxf(m, __shfl_xor(m, off));
    __shared__ float redm[16];
    __shared__ float reds[16];
    if (lane == 0) redm[wid] = m;
    __syncthreads();
    if (tid == 0) {
        float M = redm[0];
#pragma unroll
        for (int j = 1; j < 16; ++j) M = fmaxf(M, redm[j]);
        redm[0] = M;
    }
    __syncthreads();
    const float M = redm[0];

    float4 e;
    e.x = expf(v.x - M);
    e.y = expf(v.y - M);
    e.z = expf(v.z - M);
    e.w = expf(v.w - M);
    float s = e.x + e.y + e.z + e.w;
#pragma unroll
    for (int off = 32; off >= 1; off >>= 1) s += __shfl_xor(s, off);
    if (lane == 0) reds[wid] = s;
    __syncthreads();
    if (tid == 0) {
        float T = 0.f;
#pragma unroll
        for (int j = 0; j < 16; ++j) T += reds[j];
        reds[0] = T;
    }
    __syncthreads();
    const float inv = 1.0f / reds[0];
    e.x *= inv;
    e.y *= inv;
    e.z *= inv;
    e.w *= inv;
    p[tid] = e;
}

// ---------------------------------------------------------------------------
// K4: y[b][o] = sum_t attn[b][t] * x[b,t,o]   (attn ~one-hot: skip exact 0s)
// ---------------------------------------------------------------------------
__global__ __launch_bounds__(256) void wsum_kernel(const float* __restrict__ x,
                                                   const float* __restrict__ attn,
                                                   float* __restrict__ y) {
    const int c = blockIdx.x;
    const int b = blockIdx.y;
    const int tid = threadIdx.x;
    const int t0 = c * 64;
    __shared__ float a_s[64];
    if (tid < 64) a_s[tid] = attn[(size_t)b * SS + t0 + tid];
    __syncthreads();
    float acc = 0.f;
    for (int t = 0; t < 64; ++t) {
        const float a = a_s[t];
        if (a != 0.f)
            acc = fmaf(a, x[((size_t)(b * SS + t0 + t)) * DD + tid], acc);
    }
    atomicAdd(&y[b * DD + tid], acc);
}

// ---------------------------------------------------------------------------
// K5: out[b][o] = sum_i y[b][i] * W2[i][o].  grid 32 (4 b x 8 i-chunks).
// ---------------------------------------------------------------------------
__global__ __launch_bounds__(256) void out_kernel(const float* __restrict__ y,
                                                  const float* __restrict__ W2,
                                                  float* __restrict__ out) {
    const int bx = blockIdx.x;
    const int b = bx >> 3;
    const int i0 = (bx & 7) * 32;
    const int tid = threadIdx.x;
    __shared__ float y_s[32];
    if (tid < 32) y_s[tid] = y[b * DD + i0 + tid];
    __syncthreads();
    float p = 0.f;
#pragma unroll
    for (int ii = 0; ii < 32; ++ii) p = fmaf(y_s[ii], W2[(size_t)(i0 + ii) * DD + tid], p);
    atomicAdd(&out[b * DD + tid], p);
}

// ---------------------------------------------------------------------------
extern "C" void kernel_launch(void* const* d_in, const int* in_sizes, int n_in,
                              void* d_out, int out_size, void* d_ws, size_t ws_size,
                              hipStream_t stream) {
    const float* x = (const float*)d_in[0];
    const float* W0 = (const float*)d_in[1];
    const float* W1 = (const float*)d_in[2];
    const float* W2 = (const float*)d_in[3];
    float* ws = (float*)d_ws;
    float* q = ws;                    // 1024 floats
    float* scores = ws + 1024;        // 16384 floats
    float* y = ws + 1024 + 16384;     // 1024 floats
    float* out = (float*)d_out;       // 1024 floats (fp32)

    hipMemsetAsync(y, 0, BB * DD * sizeof(float), stream);
    hipMemsetAsync(d_out, 0, BB * DD * sizeof(float), stream);

    qkernel<<<dim3(BB, 8), 256, 0, stream>>>(x, W0, q);
    scores_kernel<<<dim3(1024), 256, 0, stream>>>(x, W1, q, scores);
    softmax_kernel<<<dim3(BB), 1024, 0, stream>>>(scores);
    wsum_kernel<<<dim3(64, BB), 256, 0, stream>>>(x, scores, y);
    out_kernel<<<dim3(32), 256, 0, stream>>>(y, W2, out);
}

// Round 3
// 57.382 us; speedup vs baseline: 1.2302x; 1.0882x over previous
//
#include <hip/hip_runtime.h>
#include <math.h>

#define BB 4
#define SS 4096
#define DD 256

// ---------------------------------------------------------------------------
// K1: q[b][h] = sum_i x[b,0,i] * W0[i,h]  (RoPE at pos 0 = identity)
// Also zeroes y (blocks with hc==0), replacing a memset launch.
// ---------------------------------------------------------------------------
__global__ __launch_bounds__(256) void qkernel(const float* __restrict__ x,
                                               const float* __restrict__ W0,
                                               float* __restrict__ q,
                                               float* __restrict__ y) {
    const int b = blockIdx.x;
    const int hc = blockIdx.y;
    const int tid = threadIdx.x;
    if (hc == 0) y[b * DD + tid] = 0.f;
    const int hk = tid & 31;
    const int iseg = tid >> 5;
    const int h = hc * 32 + hk;
    const float* xrow = x + (size_t)b * SS * DD;  // position-0 row
    float p = 0.f;
#pragma unroll
    for (int k = 0; k < 32; ++k) {
        const int i = iseg * 32 + k;
        p = fmaf(xrow[i], W0[i * DD + h], p);
    }
    __shared__ float red[256];
    red[tid] = p;
    __syncthreads();
    if (tid < 32) {
        float s = 0.f;
#pragma unroll
        for (int j = 0; j < 8; ++j) s += red[j * 32 + tid];
        q[b * DD + hc * 32 + tid] = s;
    }
}

// ---------------------------------------------------------------------------
// K2: scores[b][t] = q_b . R_t( x[b,t,:] @ W1 )
// grid 512 (4 b x 128 blocks of 32 rows), block 512 thr = 8 waves.
// Wave = (wr, kh): wr = row-half (16 rows), kh = k-quarter (64 k's).
// Lane l: cols 4l..4l+3 (one dwordx4 of W per k, no duplication -> 8 FLOP/B).
// x is wave-uniform: scalarized via readfirstlane -> s_load (no LDS, no VALU).
// Per-lane acc 16x4 fp32. Epilogue is linear in acc: each kh computes its
// partial RoPE-dot, 64-lane butterfly reduce, 4-way combine via 512B LDS.
// Trig expressions bit-identical to the validated rounds.
// ---------------------------------------------------------------------------
__global__ __launch_bounds__(512, 4) void scores_kernel(const float* __restrict__ x,
                                                        const float* __restrict__ W1,
                                                        const float* __restrict__ q,
                                                        float* __restrict__ scores) {
    const int tid = threadIdx.x;
    const int bid = blockIdx.x;
    const int b = bid >> 7;
    const int row0 = (bid & 127) << 5;  // 32-row block
    const int lane = tid & 63;
    const int wv = tid >> 6;
    const int wr = wv & 1;   // row half
    const int kh = wv >> 1;  // k quarter

    // wave-uniform scalar offsets (hint the backend toward SMEM loads)
    const int wroff = __builtin_amdgcn_readfirstlane(wr * 16 * DD);
    const int k0 = __builtin_amdgcn_readfirstlane(kh * 64);
    const float* xk = x + (size_t)(b * SS + row0) * DD + wroff + k0;  // rows x k
    const float* Wp = W1 + (size_t)k0 * DD + (lane << 2);

    float acc[16][4];
#pragma unroll
    for (int a = 0; a < 16; ++a)
#pragma unroll
        for (int c = 0; c < 4; ++c) acc[a][c] = 0.f;

#pragma unroll 2
    for (int kk = 0; kk < 64; ++kk) {
        const float4 w = *(const float4*)(Wp + (size_t)kk * DD);
#pragma unroll
        for (int a = 0; a < 16; ++a) {
            const float xs = xk[a * DD + kk];  // wave-uniform -> scalar load
            acc[a][0] = fmaf(xs, w.x, acc[a][0]);
            acc[a][1] = fmaf(xs, w.y, acc[a][1]);
            acc[a][2] = fmaf(xs, w.z, acc[a][2]);
            acc[a][3] = fmaf(xs, w.w, acc[a][3]);
        }
    }

    // ---- epilogue: RoPE + dot(q) on this k-partial, then 4-way combine ----
    const float4 qv = *(const float4*)(q + b * DD + (lane << 2));
    const float kfac = (float)(-9.210340371976184 / 128.0);  // -ln(1e4)/128
    const float d0 = expf((float)(2 * lane) * kfac);
    const float d1 = expf((float)(2 * lane + 1) * kfac);

    __shared__ float comb[4][32];
#pragma unroll
    for (int a = 0; a < 16; ++a) {
        const int t = row0 + wr * 16 + a;
        const float tf = (float)t;
        float s0, c0, s1, c1;
        sincosf(tf * d0, &s0, &c0);
        sincosf(tf * d1, &s1, &c1);
        float partial = qv.x * (acc[a][0] * c0 - acc[a][1] * s0)
                      + qv.y * (acc[a][0] * s0 + acc[a][1] * c0)
                      + qv.z * (acc[a][2] * c1 - acc[a][3] * s1)
                      + qv.w * (acc[a][2] * s1 + acc[a][3] * c1);
#pragma unroll
        for (int off = 32; off >= 1; off >>= 1) partial += __shfl_xor(partial, off);
        if (lane == 0) comb[kh][wr * 16 + a] = partial;
    }
    __syncthreads();
    if (tid < 32) {
        const float s = ((comb[0][tid] + comb[1][tid]) + comb[2][tid]) + comb[3][tid];
        scores[(size_t)b * SS + row0 + tid] = s;
    }
}

// ---------------------------------------------------------------------------
// K3: fused softmax + weighted row-sum. grid (64 chunks, 4 b), block 256.
// Each block recomputes the (cheap, L2-hot) global max & exp-sum over the
// b-row of raw scores, then processes its 64-t chunk: attn weights on the
// fly, skip exact-zero (underflowed) weights, atomicAdd into y.
// ---------------------------------------------------------------------------
__global__ __launch_bounds__(256) void fused_kernel(const float* __restrict__ x,
                                                    const float* __restrict__ scores,
                                                    float* __restrict__ y) {
    const int c = blockIdx.x;
    const int b = blockIdx.y;
    const int tid = threadIdx.x;
    const int lane = tid & 63;
    const int wid = tid >> 6;
    const float* sb = scores + (size_t)b * SS;

    float4 v[4];
    float m = -INFINITY;
#pragma unroll
    for (int i = 0; i < 4; ++i) {
        v[i] = *(const float4*)(sb + tid * 16 + i * 4);
        m = fmaxf(m, fmaxf(fmaxf(v[i].x, v[i].y), fmaxf(v[i].z, v[i].w)));
    }
#pragma unroll
    for (int off = 32; off >= 1; off >>= 1) m = fmaxf(m, __shfl_xor(m, off));
    __shared__ float redm[4];
    __shared__ float reds[4];
    __shared__ float a_s[64];
    if (lane == 0) redm[wid] = m;
    __syncthreads();
    const float M = fmaxf(fmaxf(redm[0], redm[1]), fmaxf(redm[2], redm[3]));

    float s = 0.f;
#pragma unroll
    for (int i = 0; i < 4; ++i) {
        s += expf(v[i].x - M);
        s += expf(v[i].y - M);
        s += expf(v[i].z - M);
        s += expf(v[i].w - M);
    }
#pragma unroll
    for (int off = 32; off >= 1; off >>= 1) s += __shfl_xor(s, off);
    if (lane == 0) reds[wid] = s;
    __syncthreads();
    const float S = ((reds[0] + reds[1]) + reds[2]) + reds[3];
    const float inv = 1.0f / S;

    if (tid < 64) a_s[tid] = expf(sb[c * 64 + tid] - M) * inv;
    __syncthreads();

    float accv = 0.f;
    for (int t = 0; t < 64; ++t) {
        const float a = a_s[t];
        if (a != 0.f)
            accv = fmaf(a, x[((size_t)(b * SS + c * 64 + t)) * DD + tid], accv);
    }
    atomicAdd(&y[b * DD + tid], accv);
}

// ---------------------------------------------------------------------------
// K4: out[b][o] = sum_i y[b][i] * W2[i][o]. grid 4, block 256, direct write.
// ---------------------------------------------------------------------------
__global__ __launch_bounds__(256) void out_kernel(const float* __restrict__ y,
                                                  const float* __restrict__ W2,
                                                  float* __restrict__ out) {
    const int b = blockIdx.x;
    const int o = threadIdx.x;
    __shared__ float y_s[DD];
    y_s[o] = y[b * DD + o];
    __syncthreads();
    float p = 0.f;
#pragma unroll 8
    for (int i = 0; i < DD; ++i) p = fmaf(y_s[i], W2[(size_t)i * DD + o], p);
    out[b * DD + o] = p;
}

// ---------------------------------------------------------------------------
extern "C" void kernel_launch(void* const* d_in, const int* in_sizes, int n_in,
                              void* d_out, int out_size, void* d_ws, size_t ws_size,
                              hipStream_t stream) {
    const float* x = (const float*)d_in[0];
    const float* W0 = (const float*)d_in[1];
    const float* W1 = (const float*)d_in[2];
    const float* W2 = (const float*)d_in[3];
    float* ws = (float*)d_ws;
    float* q = ws;                 // 1024 floats
    float* scores = ws + 1024;     // 16384 floats
    float* y = ws + 1024 + 16384;  // 1024 floats
    float* out = (float*)d_out;    // 1024 floats (fp32)

    qkernel<<<dim3(BB, 8), 256, 0, stream>>>(x, W0, q, y);
    scores_kernel<<<dim3(512), 512, 0, stream>>>(x, W1, q, scores);
    fused_kernel<<<dim3(64, BB), 256, 0, stream>>>(x, scores, y);
    out_kernel<<<dim3(BB), 256, 0, stream>>>(y, W2, out);
}